// Round 5
// baseline (118.912 us; speedup 1.0000x reference)
//
#include <hip/hip_runtime.h>
#include <hip/hip_bf16.h>
#include <math.h>

#define B_    16
#define T1_   64
#define T2_   64
#define D_    1024
#define PROJ_ 512
#define BM    64
#define BK    32
#define NT    (D_ / BK)          // 32 K-steps
#define LDP   40                 // padded A row (shorts): 80 B stride, 2-way banks = free

typedef __attribute__((ext_vector_type(8))) short bf16x8;
typedef __attribute__((ext_vector_type(4))) float f32x4;
typedef __attribute__((ext_vector_type(4))) unsigned int u32x4;

// RNE fp32->bf16, no NaN path (inputs are finite)
__device__ __forceinline__ unsigned short f2bf(float f) {
  unsigned int u = __builtin_bit_cast(unsigned int, f);
  u += 0x7FFFu + ((u >> 16) & 1u);
  return (unsigned short)(u >> 16);
}

// tanh(a) = 1 - 2/(exp(2a)+1); v_exp_f32 + v_rcp_f32, ~5 instr, |err|~1e-6
__device__ __forceinline__ float fast_tanh(float a) {
  float t = __builtin_amdgcn_exp2f(a * 2.885390081777927f);  // exp(2a)
  return 1.0f - 2.0f * __builtin_amdgcn_rcpf(t + 1.0f);
}

// ---------------------------------------------------------------------------
// Prep: Wt fragment-ordered bf16. 16B chunk index ((t*32 + n16)*64 + lane)
// holds W[k][n], n = n16*16 + (lane&15), k = t*32 + (lane>>4)*8 + j.
// ---------------------------------------------------------------------------
__global__ __launch_bounds__(256) void make_bfrag(
    const float* __restrict__ W, unsigned short* __restrict__ wt) {
  __shared__ float tile[32][33];
  const int t  = blockIdx.x;        // k-step 0..31
  const int np = blockIdx.y;        // n-pair 0..15
  const int tx = threadIdx.x & 31;
  const int ty = threadIdx.x >> 5;  // 0..7
#pragma unroll
  for (int i = 0; i < 4; ++i)
    tile[ty + i * 8][tx] =
        W[(size_t)(t * 32 + ty + i * 8) * PROJ_ + np * 32 + tx];
  __syncthreads();
  if (threadIdx.x < 128) {
    const int sub  = threadIdx.x >> 6;   // 0..1
    const int lane = threadIdx.x & 63;
    const int llo = lane & 15, lhi = lane >> 4;
    unsigned short o[8];
#pragma unroll
    for (int j = 0; j < 8; ++j)
      o[j] = f2bf(tile[lhi * 8 + j][sub * 16 + llo]);
    const int n16 = np * 2 + sub;
    *(u32x4*)(wt + ((size_t)(t * 32 + n16) * 64 + lane) * 8) = *(const u32x4*)o;
  }
}

// ---------------------------------------------------------------------------
// Fused: one (b,t1) group of 64 rows per block.
// scores = v . tanh(x @ W) via bf16 MFMA -> softmax(64) -> out = attn . x
// 512 threads = 8 waves (wid = 64-col n-slice), wave-tile 64x64, acc[4][4].
// A: depth-2 register pipeline -> bf16 LDS double-buffer.
// B: register fragments from L2-resident fragment-ordered Wt (depth-1).
// K-loop barrier: lgkmcnt(0)-only + raw s_barrier -> global prefetches stay
// in flight across the barrier (no vmcnt(0) drain); compiler inserts counted
// vmcnt at the use sites.
// ---------------------------------------------------------------------------
__global__ __launch_bounds__(512, 4) void fused_kernel(
    const float* __restrict__ x, const unsigned short* __restrict__ wt,
    const float* __restrict__ v, float* __restrict__ out) {
  __shared__ unsigned short As[2][BM][LDP];   // 10.2 KB
  __shared__ float sp[BM][9];
  __shared__ float attn[BM];
  __shared__ f32x4 xred[256];

  const int tid  = threadIdx.x;
  const int lane = tid & 63;
  const int wid  = tid >> 6;            // 0..7
  const int llo  = lane & 15, lhi = lane >> 4;
  const int bt   = blockIdx.x;
  const int m0   = bt * BM;

  f32x4 acc[4][4];
#pragma unroll
  for (int mf = 0; mf < 4; ++mf)
#pragma unroll
    for (int nf = 0; nf < 4; ++nf) acc[mf][nf] = (f32x4){0.f, 0.f, 0.f, 0.f};

  const int arow = tid >> 3, akc = (tid & 7) * 4;
  const float* asrc = x + (size_t)(m0 + arow) * D_ + akc;

  const u32x4* wt4 = (const u32x4*)wt;
  const int bbase = (wid * 4) * 64 + lane;

  // prologue: depth-2 A pipeline + B(0); As[0] staged and made visible
  float4 s0 = *(const float4*)(asrc);
  float4 s1 = *(const float4*)(asrc + BK);
  u32x4 rb[4];
#pragma unroll
  for (int nf = 0; nf < 4; ++nf) rb[nf] = wt4[bbase + nf * 64];
  {
    ushort4 ua = {f2bf(s0.x), f2bf(s0.y), f2bf(s0.z), f2bf(s0.w)};
    *(ushort4*)&As[0][arow][akc] = ua;
  }
  asm volatile("s_waitcnt lgkmcnt(0)" ::: "memory");
  __builtin_amdgcn_s_barrier();

  // Steady-state K-step: read As[BR] frags, issue A(t+2), MFMA (B refreshed
  // for t+1 after last use), convert+write A(t+1) -> As[BW], lgkm-only barrier.
#define KSTEP(T, SLD, SCV, BR, BW)                                           \
  {                                                                          \
    bf16x8 af0 = *(const bf16x8*)&As[BR][ 0 + llo][lhi * 8];                 \
    bf16x8 af1 = *(const bf16x8*)&As[BR][16 + llo][lhi * 8];                 \
    bf16x8 af2 = *(const bf16x8*)&As[BR][32 + llo][lhi * 8];                 \
    bf16x8 af3 = *(const bf16x8*)&As[BR][48 + llo][lhi * 8];                 \
    if ((T) + 2 < NT) SLD = *(const float4*)(asrc + ((T) + 2) * BK);         \
    _Pragma("unroll")                                                        \
    for (int nf = 0; nf < 4; ++nf) {                                         \
      bf16x8 bfr = *(const bf16x8*)&rb[nf];                                  \
      acc[0][nf] = __builtin_amdgcn_mfma_f32_16x16x32_bf16(af0, bfr, acc[0][nf], 0, 0, 0); \
      acc[1][nf] = __builtin_amdgcn_mfma_f32_16x16x32_bf16(af1, bfr, acc[1][nf], 0, 0, 0); \
      acc[2][nf] = __builtin_amdgcn_mfma_f32_16x16x32_bf16(af2, bfr, acc[2][nf], 0, 0, 0); \
      acc[3][nf] = __builtin_amdgcn_mfma_f32_16x16x32_bf16(af3, bfr, acc[3][nf], 0, 0, 0); \
      if ((T) + 1 < NT) rb[nf] = wt4[bbase + ((T) + 1) * 2048 + nf * 64];    \
    }                                                                        \
    if ((T) + 1 < NT) {                                                      \
      ushort4 ua = {f2bf(SCV.x), f2bf(SCV.y), f2bf(SCV.z), f2bf(SCV.w)};     \
      *(ushort4*)&As[BW][arow][akc] = ua;                                    \
    }                                                                        \
    asm volatile("s_waitcnt lgkmcnt(0)" ::: "memory");                       \
    __builtin_amdgcn_s_barrier();                                            \
  }

  for (int t = 0; t < NT; t += 2) {
    KSTEP(t,     s0, s1, 0, 1)
    KSTEP(t + 1, s1, s0, 1, 0)
  }
#undef KSTEP

  // ---- epilogue 1: tanh + dot(v-slice) + 16-lane reduce -> sp[row][wid] ----
  float vv0 = v[wid * 64 +  0 + llo];
  float vv1 = v[wid * 64 + 16 + llo];
  float vv2 = v[wid * 64 + 32 + llo];
  float vv3 = v[wid * 64 + 48 + llo];
#pragma unroll
  for (int mf = 0; mf < 4; ++mf) {
    float pr[4] = {0.f, 0.f, 0.f, 0.f};
#pragma unroll
    for (int r = 0; r < 4; ++r) {
      pr[r] += fast_tanh(acc[mf][0][r]) * vv0;
      pr[r] += fast_tanh(acc[mf][1][r]) * vv1;
      pr[r] += fast_tanh(acc[mf][2][r]) * vv2;
      pr[r] += fast_tanh(acc[mf][3][r]) * vv3;
    }
#pragma unroll
    for (int r = 0; r < 4; ++r) {
      float p = pr[r];
      p += __shfl_xor(p, 1, 64);
      p += __shfl_xor(p, 2, 64);
      p += __shfl_xor(p, 4, 64);
      p += __shfl_xor(p, 8, 64);
      if (llo == 0) sp[mf * 16 + lhi * 4 + r][wid] = p;
    }
  }
  __syncthreads();

  // ---- epilogue 2: softmax over the 64 rows (wave 0) ----
  if (tid < BM) {
    float s = 0.f;
#pragma unroll
    for (int w = 0; w < 8; ++w) s += sp[tid][w];
    float mx = s;
#pragma unroll
    for (int mask = 1; mask < 64; mask <<= 1)
      mx = fmaxf(mx, __shfl_xor(mx, mask, 64));
    const float e = __builtin_amdgcn_exp2f((s - mx) * 1.442695040888963f);
    float sum = e;
#pragma unroll
    for (int mask = 1; mask < 64; mask <<= 1)
      sum += __shfl_xor(sum, mask, 64);
    attn[tid] = e * __builtin_amdgcn_rcpf(sum);
  }
  __syncthreads();

  // ---- epilogue 3: out = sum_s attn[s]*x[m0+s][:], 2-way s-split, MLP=4 ----
  const int c4 = tid & 255;
  const int sh = tid >> 8;
  const float* xg = x + ((size_t)m0 + sh * 32) * D_ + c4 * 4;
  f32x4 o0 = {0.f,0.f,0.f,0.f}, o1 = o0, o2 = o0, o3 = o0;
#pragma unroll
  for (int s = 0; s < 32; s += 4) {
    const float w0 = attn[sh * 32 + s + 0];
    const float w1 = attn[sh * 32 + s + 1];
    const float w2 = attn[sh * 32 + s + 2];
    const float w3 = attn[sh * 32 + s + 3];
    const float4 a0 = *(const float4*)(xg + (size_t)(s + 0) * D_);
    const float4 a1 = *(const float4*)(xg + (size_t)(s + 1) * D_);
    const float4 a2 = *(const float4*)(xg + (size_t)(s + 2) * D_);
    const float4 a3 = *(const float4*)(xg + (size_t)(s + 3) * D_);
    o0[0] += w0 * a0.x; o0[1] += w0 * a0.y; o0[2] += w0 * a0.z; o0[3] += w0 * a0.w;
    o1[0] += w1 * a1.x; o1[1] += w1 * a1.y; o1[2] += w1 * a1.z; o1[3] += w1 * a1.w;
    o2[0] += w2 * a2.x; o2[1] += w2 * a2.y; o2[2] += w2 * a2.z; o2[3] += w2 * a2.w;
    o3[0] += w3 * a3.x; o3[1] += w3 * a3.y; o3[2] += w3 * a3.z; o3[3] += w3 * a3.w;
  }
  f32x4 o;
#pragma unroll
  for (int j = 0; j < 4; ++j) o[j] = (o0[j] + o1[j]) + (o2[j] + o3[j]);
  if (sh == 1) xred[c4] = o;
  __syncthreads();
  if (sh == 0) {
    f32x4 o2b = xred[c4];
    float4 res = {o[0] + o2b[0], o[1] + o2b[1], o[2] + o2b[2], o[3] + o2b[3]};
    *(float4*)(out + (size_t)bt * D_ + c4 * 4) = res;
  }
}

extern "C" void kernel_launch(void* const* d_in, const int* in_sizes, int n_in,
                              void* d_out, int out_size, void* d_ws, size_t ws_size,
                              hipStream_t stream) {
  const float* x = (const float*)d_in[0];   // (16,64,64,1024) fp32
  const float* W = (const float*)d_in[1];   // (1024,512) fp32
  const float* v = (const float*)d_in[2];   // (512,) fp32
  float* out = (float*)d_out;               // (16,64,1024) fp32
  unsigned short* Wt = (unsigned short*)d_ws;  // 1 MB fragment-ordered bf16

  make_bfrag<<<dim3(NT, PROJ_ / 32), 256, 0, stream>>>(W, Wt);
  fused_kernel<<<B_ * T1_, 512, 0, stream>>>(x, Wt, v, out);
}